// Round 4
// baseline (686.880 us; speedup 1.0000x reference)
//
#include <hip/hip_runtime.h>
#include <cstdint>
#include <cstddef>

// Problem constants
#define BB 4096
#define DD 2048
#define NHH 16
#define NTT 4
#define DKK 128

using u16 = unsigned short;
using u32 = unsigned int;

typedef __bf16 bf16x8 __attribute__((ext_vector_type(8)));
typedef float f32x4 __attribute__((ext_vector_type(4)));

__device__ __forceinline__ float b2f(u16 u) {
    union { float f; u32 i; } c; c.i = ((u32)u) << 16; return c.f;
}
__device__ __forceinline__ u16 f2b(float f) {
    union { float f; u32 i; } c; c.f = f;
    u32 x = c.i;
    u32 r = (x + 0x7fffu + ((x >> 16) & 1u)) >> 16;  // RNE
    return (u16)r;
}
// pack two f32 -> two bf16 (round-half-up via +0x8000, v_perm byte select)
__device__ __forceinline__ u32 pk(float lo, float hi) {
    u32 a = __builtin_bit_cast(u32, lo) + 0x8000u;
    u32 b = __builtin_bit_cast(u32, hi) + 0x8000u;
    return __builtin_amdgcn_perm(b, a, 0x07060302u);  // {b[31:16], a[31:16]}
}

__device__ __forceinline__ void load_lds16(const void* g, void* l) {
    __builtin_amdgcn_global_load_lds((const __attribute__((address_space(1))) void*)g,
                                     (__attribute__((address_space(3))) void*)l,
                                     16, 0, 0);
}

// ---------------------------------------------------------------------------
// cvt_all: blocks 0..4095: one block per BATCH -> converts 4 evidence rows to
// Ebf (M-interleaved rows 4b+t) AND writes resid = 0.25*sum_t H (f32), so
// ln_kernel does not re-read 134 MB of f32 evidence.
// blocks 4096..12287: weights Wq/Wk/Wv/Wo -> W4 (2048 rows each).
// ---------------------------------------------------------------------------
__global__ __launch_bounds__(256) void cvt_all(
    const float* __restrict__ e0, const float* __restrict__ e1,
    const float* __restrict__ e2, const float* __restrict__ e3,
    const float* __restrict__ Wq, const float* __restrict__ Wk,
    const float* __restrict__ Wv, const float* __restrict__ Wo,
    u16* __restrict__ Ebf, u16* __restrict__ W4, float* __restrict__ resid)
{
    const int blk = blockIdx.x;
    const int tid = threadIdx.x;
    if (blk < 4096) {
        const int b = blk;
        const int c = tid * 8;
        const size_t rb = (size_t)b * DD + c;
        const float* eps[4] = {e0, e1, e2, e3};
        float a8[8] = {0, 0, 0, 0, 0, 0, 0, 0};
#pragma unroll
        for (int t = 0; t < 4; ++t) {
            float4 p0 = *(const float4*)(eps[t] + rb);
            float4 p1 = *(const float4*)(eps[t] + rb + 4);
            u16* dst = Ebf + ((size_t)(b * 4 + t)) * DD + c;
            *(uint4*)dst = make_uint4(pk(p0.x, p0.y), pk(p0.z, p0.w),
                                      pk(p1.x, p1.y), pk(p1.z, p1.w));
            a8[0] += p0.x; a8[1] += p0.y; a8[2] += p0.z; a8[3] += p0.w;
            a8[4] += p1.x; a8[5] += p1.y; a8[6] += p1.z; a8[7] += p1.w;
        }
        *(float4*)(resid + rb)     = make_float4(a8[0] * 0.25f, a8[1] * 0.25f,
                                                 a8[2] * 0.25f, a8[3] * 0.25f);
        *(float4*)(resid + rb + 4) = make_float4(a8[4] * 0.25f, a8[5] * 0.25f,
                                                 a8[6] * 0.25f, a8[7] * 0.25f);
    } else {
        const int wb = blk - 4096;           // 0..8191
        const int w = wb >> 11;              // 0..3
        const float* src = (w == 0) ? Wq : (w == 1) ? Wk : (w == 2) ? Wv : Wo;
        u16* dst = W4 + (size_t)w * DD * DD;
        const size_t i = (size_t)(wb & 2047) * 2048 + tid * 8;
        float4 a = *(const float4*)(src + i);
        float4 c2 = *(const float4*)(src + i + 4);
        *(uint4*)(dst + i) = make_uint4(pk(a.x, a.y), pk(a.z, a.w),
                                        pk(c2.x, c2.y), pk(c2.z, c2.w));
    }
}

// ---------------------------------------------------------------------------
// qkv_attn: fused Q/K/V projection + quality-gated softmax + V-combine.
// grid (16, 128): x = head h (n-tile = 128 cols = one head), y = m-tile.
//
// 2-phase double-buffered pipeline (catalog T3 minimum recipe), BK=32:
//   STAGE(next tile -> other buffer); COMPUTE(current); __syncthreads();
// One barrier per K-iter; the barrier's implicit vmcnt(0) drain lands a full
// MFMA phase (~466 cyc/SIMD) after the loads were issued -> latency hidden.
// LDS = 4 tiles x 2 bufs x 8KB + exch = 68KB -> keeps 2 blocks/CU.
//
// BK=32 swizzle (64B rows, 4 x 16B slots): LDS[row][s] holds global chunk
// s ^ ((row>>1)&3).  Staging (rule #21): one wave call writes 16 rows
// linearly; lane l -> row +(l>>2), slot l&3, so source chunk = (l&3)^((l>>3)&3)
// is lane-constant.  Fragment reads use slot' = q4 ^ ((lrow>>1)&3): uniform
// 8 lanes per bank-quad (same uniformity class as the BK=64 swizzle that
// measured 0 conflicts).
//
// Wave tiling 2x2 of 64M x 64N; Q/K/V MFMA groups sequenced with
// sched_barrier(0) to bound B-frag liveness (R3's proven anti-spill).
// Score dot completes via LDS exchange between N-partner waves (w^1).
// ---------------------------------------------------------------------------
#define QKV_COMPUTE(BI)                                                        \
    {                                                                          \
        bf16x8 af[4];                                                          \
        _Pragma("unroll")                                                      \
        for (int mi = 0; mi < 4; ++mi)                                         \
            af[mi] = *(const bf16x8*)((const char*)As[BI] +                    \
                     (wm + mi * 16 + lrow) * 64 + soff);                       \
        {                                                                      \
            bf16x8 b4[4];                                                      \
            _Pragma("unroll")                                                  \
            for (int ni = 0; ni < 4; ++ni)                                     \
                b4[ni] = *(const bf16x8*)((const char*)BQs[BI] +               \
                         (wn + ni * 16 + lrow) * 64 + soff);                   \
            _Pragma("unroll")                                                  \
            for (int mi = 0; mi < 4; ++mi)                                     \
                _Pragma("unroll")                                              \
                for (int ni = 0; ni < 4; ++ni)                                 \
                    aQ[mi][ni] = __builtin_amdgcn_mfma_f32_16x16x32_bf16(      \
                        af[mi], b4[ni], aQ[mi][ni], 0, 0, 0);                  \
        }                                                                      \
        __builtin_amdgcn_sched_barrier(0);                                     \
        {                                                                      \
            bf16x8 b4[4];                                                      \
            _Pragma("unroll")                                                  \
            for (int ni = 0; ni < 4; ++ni)                                     \
                b4[ni] = *(const bf16x8*)((const char*)BKs[BI] +               \
                         (wn + ni * 16 + lrow) * 64 + soff);                   \
            _Pragma("unroll")                                                  \
            for (int mi = 0; mi < 4; ++mi)                                     \
                _Pragma("unroll")                                              \
                for (int ni = 0; ni < 4; ++ni)                                 \
                    aK[mi][ni] = __builtin_amdgcn_mfma_f32_16x16x32_bf16(      \
                        af[mi], b4[ni], aK[mi][ni], 0, 0, 0);                  \
        }                                                                      \
        __builtin_amdgcn_sched_barrier(0);                                     \
        {                                                                      \
            bf16x8 b4[4];                                                      \
            _Pragma("unroll")                                                  \
            for (int ni = 0; ni < 4; ++ni)                                     \
                b4[ni] = *(const bf16x8*)((const char*)BVs[BI] +               \
                         (wn + ni * 16 + lrow) * 64 + soff);                   \
            _Pragma("unroll")                                                  \
            for (int mi = 0; mi < 4; ++mi)                                     \
                _Pragma("unroll")                                              \
                for (int ni = 0; ni < 4; ++ni)                                 \
                    aV[mi][ni] = __builtin_amdgcn_mfma_f32_16x16x32_bf16(      \
                        af[mi], b4[ni], aV[mi][ni], 0, 0, 0);                  \
        }                                                                      \
        __builtin_amdgcn_sched_barrier(0);                                     \
    }

#define QKV_STAGE(BI, KT)                                                      \
    {                                                                          \
        const size_t ko = (size_t)(KT) * 32;                                   \
        char* dA = (char*)As[BI]  + wave * 1024;                               \
        char* dQ = (char*)BQs[BI] + wave * 1024;                               \
        char* dK = (char*)BKs[BI] + wave * 1024;                               \
        char* dV = (char*)BVs[BI] + wave * 1024;                               \
        load_lds16(srcA + ko, dA);       load_lds16(srcA + ko + D64, dA + 4096);\
        load_lds16(srcQ + ko, dQ);       load_lds16(srcQ + ko + D64, dQ + 4096);\
        load_lds16(srcK + ko, dK);       load_lds16(srcK + ko + D64, dK + 4096);\
        load_lds16(srcV + ko, dV);       load_lds16(srcV + ko + D64, dV + 4096);\
    }

__global__ __launch_bounds__(256, 2) void qkv_attn(
    const u16* __restrict__ Ebf,
    const u16* __restrict__ Wqb, const u16* __restrict__ Wkb,
    const u16* __restrict__ Wvb,
    const float* __restrict__ bq, const float* __restrict__ bk,
    const float* __restrict__ bv, const float* __restrict__ qual,
    u16* __restrict__ ctx)
{
    __shared__ __align__(16) u16 As [2][128 * 32];
    __shared__ __align__(16) u16 BQs[2][128 * 32];
    __shared__ __align__(16) u16 BKs[2][128 * 32];
    __shared__ __align__(16) u16 BVs[2][128 * 32];
    __shared__ float exch[4][4][4][16];   // [wave][mi][quad][t*4+j]

    const int tid = threadIdx.x;
    const int h = blockIdx.x;            // head = n-tile
    const int m0 = blockIdx.y * 128;
    const int n0 = h * 128;

    const int wave = tid >> 6;
    const int lane = tid & 63;

    // staging geometry (see header comment)
    const int srow = wave * 16 + (lane >> 2);
    const int scol = ((lane & 3) ^ ((lane >> 3) & 3)) * 8;   // u16 units
    const u16* srcA = Ebf + (size_t)(m0 + srow) * DD + scol;
    const u16* srcQ = Wqb + (size_t)(n0 + srow) * DD + scol;
    const u16* srcK = Wkb + (size_t)(n0 + srow) * DD + scol;
    const u16* srcV = Wvb + (size_t)(n0 + srow) * DD + scol;
    const size_t D64 = (size_t)64 * DD;

    const int lrow = lane & 15;
    const int q4 = lane >> 4;
    const int wm = (wave >> 1) * 64;     // wave's 64 M-rows
    const int wn = (wave & 1) * 64;      // wave's 64 N-cols (half head)
    const int soff = (q4 ^ ((lrow >> 1) & 3)) * 16;  // swizzled slot in 64B row

    f32x4 aQ[4][4] = {};
    f32x4 aK[4][4] = {};
    f32x4 aV[4][4] = {};

    QKV_STAGE(0, 0);
    __syncthreads();

#pragma unroll 1
    for (int it = 0; it < 64; it += 2) {
        QKV_STAGE(1, it + 1);
        QKV_COMPUTE(0);
        __syncthreads();
        if (it + 2 < 64) QKV_STAGE(0, it + 2);
        QKV_COMPUTE(1);
        __syncthreads();
    }

    // ---- epilogue: scores -> cross-wave sum -> softmax -> V combine ----
    const int quad = lane >> 4;
    const int lcol = lane & 15;

    float qb[4], kb[4], vb[4];
#pragma unroll
    for (int ni = 0; ni < 4; ++ni) {
        const int col = n0 + wn + ni * 16 + lcol;
        qb[ni] = bq[col]; kb[ni] = bk[col]; vb[ni] = bv[col];
    }

    // Phase A: per mi, partial scores over this wave's 64 cols -> exch
#pragma unroll
    for (int mi = 0; mi < 4; ++mi) {
        float ps[4][4];
#pragma unroll
        for (int t = 0; t < 4; ++t)
#pragma unroll
            for (int j = 0; j < 4; ++j) ps[t][j] = 0.f;

#pragma unroll
        for (int ni = 0; ni < 4; ++ni) {
            float qv[4], kv[4];
#pragma unroll
            for (int t = 0; t < 4; ++t) {
                qv[t] = aQ[mi][ni][t] + qb[ni];
                kv[t] = aK[mi][ni][t] + kb[ni];
            }
#pragma unroll
            for (int t = 0; t < 4; ++t)
#pragma unroll
                for (int j = 0; j < 4; ++j) ps[t][j] += qv[t] * kv[j];
        }
        // butterfly over the 16 col-lanes (bits 0..3 of lane)
#pragma unroll
        for (int t = 0; t < 4; ++t)
#pragma unroll
            for (int j = 0; j < 4; ++j) {
                ps[t][j] += __shfl_xor(ps[t][j], 1);
                ps[t][j] += __shfl_xor(ps[t][j], 2);
                ps[t][j] += __shfl_xor(ps[t][j], 4);
                ps[t][j] += __shfl_xor(ps[t][j], 8);
            }
        // one lane per quad writes the 16 values with STATIC indices
        if (lcol == 0) {
#pragma unroll
            for (int t = 0; t < 4; ++t)
#pragma unroll
                for (int j = 0; j < 4; ++j)
                    exch[wave][mi][quad][t * 4 + j] = ps[t][j];
        }
    }
    __syncthreads();

    // Phase B: full scores (own + N-partner) -> softmax -> V combine
    const float scale = 0.08838834764831845f;   // 1/sqrt(128)
#pragma unroll
    for (int mi = 0; mi < 4; ++mi) {
        const int bbat = (m0 >> 2) + (wave >> 1) * 16 + mi * 4 + quad;

        float s16[16];
#pragma unroll
        for (int v = 0; v < 16; ++v)
            s16[v] = exch[wave][mi][quad][v] + exch[wave ^ 1][mi][quad][v];

        float qj[4];
#pragma unroll
        for (int j = 0; j < 4; ++j) qj[j] = qual[bbat * 4 + j] * scale;

        float wsum[4] = {0.f, 0.f, 0.f, 0.f};
#pragma unroll
        for (int t = 0; t < 4; ++t) {
            float sm[4]; float mx = -1e30f;
#pragma unroll
            for (int j = 0; j < 4; ++j) { sm[j] = s16[t * 4 + j] * qj[j]; mx = fmaxf(mx, sm[j]); }
            float ex[4]; float se = 0.f;
#pragma unroll
            for (int j = 0; j < 4; ++j) { ex[j] = __expf(sm[j] - mx); se += ex[j]; }
            const float inv = 0.25f / se;
#pragma unroll
            for (int j = 0; j < 4; ++j) wsum[j] += ex[j] * inv;
        }

        // ctx[bbat][col] = sum_j wsum[j] * Vproj[4b+j][col] + bv[col]
        // (sum_j wsum[j] == 1, so bias coefficient is exactly 1)
#pragma unroll
        for (int ni = 0; ni < 4; ++ni) {
            const int col = n0 + wn + ni * 16 + lcol;
            float r = wsum[0] * aV[mi][ni][0] + wsum[1] * aV[mi][ni][1]
                    + wsum[2] * aV[mi][ni][2] + wsum[3] * aV[mi][ni][3] + vb[ni];
            ctx[(size_t)bbat * DD + col] = f2b(r);
        }
    }
}

// ---------------------------------------------------------------------------
// o_gemm: Y (f32) = ctx @ Wo^T + bo.  Same 2-phase BK=32 dbuf structure.
// LDS 32KB -> up to 4 blocks/CU.
// ---------------------------------------------------------------------------
#define O_STAGE(BI, KT)                                                        \
    {                                                                          \
        const size_t ko = (size_t)(KT) * 32;                                   \
        char* dA = (char*)As[BI] + wave * 1024;                                \
        char* dB = (char*)Bs[BI] + wave * 1024;                                \
        load_lds16(srcA + ko, dA);      load_lds16(srcA + ko + D64, dA + 4096);\
        load_lds16(srcB + ko, dB);      load_lds16(srcB + ko + D64, dB + 4096);\
    }

#define O_COMPUTE(BI)                                                          \
    {                                                                          \
        bf16x8 af[4], bfr[4];                                                  \
        _Pragma("unroll")                                                      \
        for (int i = 0; i < 4; ++i)                                            \
            af[i] = *(const bf16x8*)((const char*)As[BI] +                     \
                    (wm + i * 16 + lrow) * 64 + soff);                         \
        _Pragma("unroll")                                                      \
        for (int i = 0; i < 4; ++i)                                            \
            bfr[i] = *(const bf16x8*)((const char*)Bs[BI] +                    \
                     (wn + i * 16 + lrow) * 64 + soff);                        \
        _Pragma("unroll")                                                      \
        for (int mi = 0; mi < 4; ++mi)                                         \
            _Pragma("unroll")                                                  \
            for (int ni = 0; ni < 4; ++ni)                                     \
                acc[mi][ni] = __builtin_amdgcn_mfma_f32_16x16x32_bf16(         \
                    af[mi], bfr[ni], acc[mi][ni], 0, 0, 0);                    \
    }

__global__ __launch_bounds__(256) void o_gemm(
    const u16* __restrict__ A, const u16* __restrict__ W,
    const float* __restrict__ bia, float* __restrict__ Y)
{
    __shared__ __align__(16) u16 As[2][128 * 32];
    __shared__ __align__(16) u16 Bs[2][128 * 32];

    const int tid = threadIdx.x;
    const int m0 = blockIdx.x * 128;
    const int n0 = blockIdx.y * 128;

    const int wave = tid >> 6;
    const int lane = tid & 63;

    const int srow = wave * 16 + (lane >> 2);
    const int scol = ((lane & 3) ^ ((lane >> 3) & 3)) * 8;
    const u16* srcA = A + (size_t)(m0 + srow) * DD + scol;
    const u16* srcB = W + (size_t)(n0 + srow) * DD + scol;
    const size_t D64 = (size_t)64 * DD;

    const int wm = (wave >> 1) * 64;
    const int wn = (wave & 1) * 64;
    const int lrow = lane & 15;
    const int q4 = lane >> 4;
    const int soff = (q4 ^ ((lrow >> 1) & 3)) * 16;

    f32x4 acc[4][4] = {};

    O_STAGE(0, 0);
    __syncthreads();

#pragma unroll 1
    for (int it = 0; it < 64; it += 2) {
        O_STAGE(1, it + 1);
        O_COMPUTE(0);
        __syncthreads();
        if (it + 2 < 64) O_STAGE(0, it + 2);
        O_COMPUTE(1);
        __syncthreads();
    }

#pragma unroll
    for (int mi = 0; mi < 4; ++mi) {
#pragma unroll
        for (int r = 0; r < 4; ++r) {
            const int grow = m0 + wm + mi * 16 + (lane >> 4) * 4 + r;
#pragma unroll
            for (int ni = 0; ni < 4; ++ni) {
                const int gcol = n0 + wn + ni * 16 + (lane & 15);
                Y[(size_t)grow * DD + gcol] = acc[mi][ni][r] + bia[gcol];
            }
        }
    }
}

// ---------------------------------------------------------------------------
// ln_kernel: residual add (precomputed resid) + LayerNorm.  One block per row.
// ---------------------------------------------------------------------------
__global__ __launch_bounds__(256) void ln_kernel(
    const float* __restrict__ Y,
    const float* __restrict__ resid,
    const float* __restrict__ gamma, const float* __restrict__ beta,
    float* __restrict__ out)
{
    const int r = blockIdx.x;
    const int tid = threadIdx.x;
    const int c = tid * 8;
    const size_t base = (size_t)r * DD + c;

    float v[8];
    {
        float4 y0 = *(const float4*)(Y + base);
        float4 y1 = *(const float4*)(Y + base + 4);
        float4 r0 = *(const float4*)(resid + base);
        float4 r1 = *(const float4*)(resid + base + 4);
        v[0] = y0.x + r0.x; v[1] = y0.y + r0.y; v[2] = y0.z + r0.z; v[3] = y0.w + r0.w;
        v[4] = y1.x + r1.x; v[5] = y1.y + r1.y; v[6] = y1.z + r1.z; v[7] = y1.w + r1.w;
    }

    float s = 0.f, sq = 0.f;
#pragma unroll
    for (int i = 0; i < 8; ++i) { s += v[i]; sq += v[i] * v[i]; }
#pragma unroll
    for (int off = 32; off >= 1; off >>= 1) {
        s += __shfl_xor(s, off);
        sq += __shfl_xor(sq, off);
    }
    __shared__ float sh[8];
    const int lane = tid & 63, wv = tid >> 6;
    if (lane == 0) { sh[wv] = s; sh[4 + wv] = sq; }
    __syncthreads();
    s = sh[0] + sh[1] + sh[2] + sh[3];
    sq = sh[4] + sh[5] + sh[6] + sh[7];

    const float invD = 1.0f / 2048.0f;
    const float mu = s * invD;
    const float rs = rsqrtf(sq * invD - mu * mu + 1e-5f);

    float4 g0 = *(const float4*)(gamma + c);
    float4 g1 = *(const float4*)(gamma + c + 4);
    float4 b0 = *(const float4*)(beta + c);
    float4 b1 = *(const float4*)(beta + c + 4);
    float gg[8] = {g0.x, g0.y, g0.z, g0.w, g1.x, g1.y, g1.z, g1.w};
    float bb[8] = {b0.x, b0.y, b0.z, b0.w, b1.x, b1.y, b1.z, b1.w};

    float o[8];
#pragma unroll
    for (int i = 0; i < 8; ++i) o[i] = (v[i] - mu) * rs * gg[i] + bb[i];
    *(float4*)(out + base)     = make_float4(o[0], o[1], o[2], o[3]);
    *(float4*)(out + base + 4) = make_float4(o[4], o[5], o[6], o[7]);
}

// ---------------------------------------------------------------------------
extern "C" void kernel_launch(void* const* d_in, const int* in_sizes, int n_in,
                              void* d_out, int out_size, void* d_ws, size_t ws_size,
                              hipStream_t stream)
{
    const float* e0   = (const float*)d_in[0];
    const float* e1   = (const float*)d_in[1];
    const float* e2   = (const float*)d_in[2];
    const float* e3   = (const float*)d_in[3];
    const float* qual = (const float*)d_in[4];
    const float* Wq   = (const float*)d_in[5];
    const float* bq   = (const float*)d_in[6];
    const float* Wk   = (const float*)d_in[7];
    const float* bk   = (const float*)d_in[8];
    const float* Wv   = (const float*)d_in[9];
    const float* bv   = (const float*)d_in[10];
    const float* Wo   = (const float*)d_in[11];
    const float* bo   = (const float*)d_in[12];
    const float* gm   = (const float*)d_in[13];
    const float* bt   = (const float*)d_in[14];

    const size_t WD = (size_t)DD * DD;            // 4,194,304
    const size_t MQ = (size_t)BB * NTT * DD;      // 33,554,432
    const size_t ED = (size_t)BB * DD;            // 8,388,608

    // workspace (u16 units): Ebf 67.1MB + W4 33.6MB + ctx 16.8MB
    // + Y 33.6MB f32 + resid 33.6MB f32 = 184.6 MB total.
    u16* Ebf = (u16*)d_ws;                        // MQ
    u16* W4  = Ebf + MQ;                          // 4*WD  (q,k,v,o)
    u16* ctx = W4 + 4 * WD;                       // ED
    float* Y = (float*)(ctx + ED);                // ED floats
    float* resid = Y + ED;                        // ED floats

    // stage 0: all conversions + residual mean in one dispatch
    cvt_all<<<dim3(12288), 256, 0, stream>>>(e0, e1, e2, e3, Wq, Wk, Wv, Wo,
                                             Ebf, W4, resid);

    // stage 1: fused QKV projection + attention -> ctx (B x D)
    qkv_attn<<<dim3(16, 128), 256, 0, stream>>>(Ebf, W4, W4 + WD, W4 + 2 * WD,
                                                bq, bk, bv, qual, ctx);

    // stage 2: O projection -> Y f32
    o_gemm<<<dim3(32, 16), 256, 0, stream>>>(ctx, W4 + 3 * WD, bo, Y);

    // stage 3: residual add + LayerNorm
    ln_kernel<<<dim3(4096), 256, 0, stream>>>(Y, resid, gm, bt,
                                              (float*)d_out);
}

// Round 5
// 664.708 us; speedup vs baseline: 1.0334x; 1.0334x over previous
//
#include <hip/hip_runtime.h>
#include <cstdint>
#include <cstddef>

// Problem constants
#define BB 4096
#define DD 2048
#define NHH 16
#define NTT 4
#define DKK 128

using u16 = unsigned short;
using u32 = unsigned int;

typedef __bf16 bf16x8 __attribute__((ext_vector_type(8)));
typedef float f32x4 __attribute__((ext_vector_type(4)));

__device__ __forceinline__ float b2f(u16 u) {
    union { float f; u32 i; } c; c.i = ((u32)u) << 16; return c.f;
}
__device__ __forceinline__ u16 f2b(float f) {
    union { float f; u32 i; } c; c.f = f;
    u32 x = c.i;
    u32 r = (x + 0x7fffu + ((x >> 16) & 1u)) >> 16;  // RNE
    return (u16)r;
}
// pack two f32 -> two bf16 (round-half-up via +0x8000, v_perm byte select)
__device__ __forceinline__ u32 pk(float lo, float hi) {
    u32 a = __builtin_bit_cast(u32, lo) + 0x8000u;
    u32 b = __builtin_bit_cast(u32, hi) + 0x8000u;
    return __builtin_amdgcn_perm(b, a, 0x07060302u);  // {b[31:16], a[31:16]}
}

__device__ __forceinline__ void load_lds16(const void* g, void* l) {
    __builtin_amdgcn_global_load_lds((const __attribute__((address_space(1))) void*)g,
                                     (__attribute__((address_space(3))) void*)l,
                                     16, 0, 0);
}

// Counted-vmcnt pipeline barriers (T4): raw s_barrier, never vmcnt(0) in the
// main loop.  asm memory clobbers order LDS/global ops; sched_barrier(0)
// fences MFMA hoisting (rule #18).
#define PIPE_WAIT(N) do {                                                      \
    asm volatile("s_waitcnt vmcnt(" #N ")" ::: "memory");                      \
    __builtin_amdgcn_sched_barrier(0);                                         \
    __builtin_amdgcn_s_barrier();                                              \
    __builtin_amdgcn_sched_barrier(0); } while (0)

#define PIPE_FLIP() do {                                                       \
    asm volatile("s_waitcnt lgkmcnt(0)" ::: "memory");                         \
    __builtin_amdgcn_sched_barrier(0);                                         \
    __builtin_amdgcn_s_barrier();                                              \
    __builtin_amdgcn_sched_barrier(0); } while (0)

// ---------------------------------------------------------------------------
// cvt_all: blocks 0..4095: one block per BATCH -> converts 4 evidence rows to
// Ebf (M-interleaved rows 4b+t) AND writes resid = 0.25*sum_t H (f32), so
// ln_kernel does not re-read 134 MB of f32 evidence.
// blocks 4096..12287: weights Wq/Wk/Wv/Wo -> W4 (2048 rows each).
// ---------------------------------------------------------------------------
__global__ __launch_bounds__(256) void cvt_all(
    const float* __restrict__ e0, const float* __restrict__ e1,
    const float* __restrict__ e2, const float* __restrict__ e3,
    const float* __restrict__ Wq, const float* __restrict__ Wk,
    const float* __restrict__ Wv, const float* __restrict__ Wo,
    u16* __restrict__ Ebf, u16* __restrict__ W4, float* __restrict__ resid)
{
    const int blk = blockIdx.x;
    const int tid = threadIdx.x;
    if (blk < 4096) {
        const int b = blk;
        const int c = tid * 8;
        const size_t rb = (size_t)b * DD + c;
        const float* eps[4] = {e0, e1, e2, e3};
        float a8[8] = {0, 0, 0, 0, 0, 0, 0, 0};
#pragma unroll
        for (int t = 0; t < 4; ++t) {
            float4 p0 = *(const float4*)(eps[t] + rb);
            float4 p1 = *(const float4*)(eps[t] + rb + 4);
            u16* dst = Ebf + ((size_t)(b * 4 + t)) * DD + c;
            *(uint4*)dst = make_uint4(pk(p0.x, p0.y), pk(p0.z, p0.w),
                                      pk(p1.x, p1.y), pk(p1.z, p1.w));
            a8[0] += p0.x; a8[1] += p0.y; a8[2] += p0.z; a8[3] += p0.w;
            a8[4] += p1.x; a8[5] += p1.y; a8[6] += p1.z; a8[7] += p1.w;
        }
        *(float4*)(resid + rb)     = make_float4(a8[0] * 0.25f, a8[1] * 0.25f,
                                                 a8[2] * 0.25f, a8[3] * 0.25f);
        *(float4*)(resid + rb + 4) = make_float4(a8[4] * 0.25f, a8[5] * 0.25f,
                                                 a8[6] * 0.25f, a8[7] * 0.25f);
    } else {
        const int wb = blk - 4096;           // 0..8191
        const int w = wb >> 11;              // 0..3
        const float* src = (w == 0) ? Wq : (w == 1) ? Wk : (w == 2) ? Wv : Wo;
        u16* dst = W4 + (size_t)w * DD * DD;
        const size_t i = (size_t)(wb & 2047) * 2048 + tid * 8;
        float4 a = *(const float4*)(src + i);
        float4 c2 = *(const float4*)(src + i + 4);
        *(uint4*)(dst + i) = make_uint4(pk(a.x, a.y), pk(a.z, a.w),
                                        pk(c2.x, c2.y), pk(c2.z, c2.w));
    }
}

// ---------------------------------------------------------------------------
// qkv_attn: fused Q/K/V projection + quality-gated softmax + V-combine.
// grid (16, 128): x = head h (n-tile = 128 cols = one head), y = m-tile.
//
// BK=32 double-buffered with COUNTED vmcnt (T3+T4): per tile phase
//   vmcnt(8)+bar -> COMPUTE(buf) -> lgkmcnt(0)+bar -> STAGE(buf, t+2)
// so one STAGE (8 loads/wave) stays in flight across two barriers (~a full
// 48-MFMA phase).  __syncthreads (which drains vmcnt(0)) never appears in
// the K-loop.  LDS 68KB -> 2 blocks/CU.
//
// BK=32 swizzle (64B rows, 4 x 16B slots): LDS[row][s] holds global chunk
// s ^ ((row>>1)&3); staging source chunk = (l&3)^((l>>3)&3) is lane-constant
// (rule #21); fragment reads use slot' = q4 ^ ((lrow>>1)&3) -> 0 conflicts
// (verified R4).
//
// Wave tiling 2x2 of 64M x 64N; Q/K/V MFMA groups sequenced with
// sched_barrier(0) to bound B-frag liveness (R3's proven anti-spill).
// Score dot completes via LDS exchange between N-partner waves (w^1).
// ---------------------------------------------------------------------------
#define QKV_COMPUTE(BI)                                                        \
    {                                                                          \
        bf16x8 af[4];                                                          \
        _Pragma("unroll")                                                      \
        for (int mi = 0; mi < 4; ++mi)                                         \
            af[mi] = *(const bf16x8*)((const char*)As[BI] +                    \
                     (wm + mi * 16 + lrow) * 64 + soff);                       \
        {                                                                      \
            bf16x8 b4[4];                                                      \
            _Pragma("unroll")                                                  \
            for (int ni = 0; ni < 4; ++ni)                                     \
                b4[ni] = *(const bf16x8*)((const char*)BQs[BI] +               \
                         (wn + ni * 16 + lrow) * 64 + soff);                   \
            _Pragma("unroll")                                                  \
            for (int mi = 0; mi < 4; ++mi)                                     \
                _Pragma("unroll")                                              \
                for (int ni = 0; ni < 4; ++ni)                                 \
                    aQ[mi][ni] = __builtin_amdgcn_mfma_f32_16x16x32_bf16(      \
                        af[mi], b4[ni], aQ[mi][ni], 0, 0, 0);                  \
        }                                                                      \
        __builtin_amdgcn_sched_barrier(0);                                     \
        {                                                                      \
            bf16x8 b4[4];                                                      \
            _Pragma("unroll")                                                  \
            for (int ni = 0; ni < 4; ++ni)                                     \
                b4[ni] = *(const bf16x8*)((const char*)BKs[BI] +               \
                         (wn + ni * 16 + lrow) * 64 + soff);                   \
            _Pragma("unroll")                                                  \
            for (int mi = 0; mi < 4; ++mi)                                     \
                _Pragma("unroll")                                              \
                for (int ni = 0; ni < 4; ++ni)                                 \
                    aK[mi][ni] = __builtin_amdgcn_mfma_f32_16x16x32_bf16(      \
                        af[mi], b4[ni], aK[mi][ni], 0, 0, 0);                  \
        }                                                                      \
        __builtin_amdgcn_sched_barrier(0);                                     \
        {                                                                      \
            bf16x8 b4[4];                                                      \
            _Pragma("unroll")                                                  \
            for (int ni = 0; ni < 4; ++ni)                                     \
                b4[ni] = *(const bf16x8*)((const char*)BVs[BI] +               \
                         (wn + ni * 16 + lrow) * 64 + soff);                   \
            _Pragma("unroll")                                                  \
            for (int mi = 0; mi < 4; ++mi)                                     \
                _Pragma("unroll")                                              \
                for (int ni = 0; ni < 4; ++ni)                                 \
                    aV[mi][ni] = __builtin_amdgcn_mfma_f32_16x16x32_bf16(      \
                        af[mi], b4[ni], aV[mi][ni], 0, 0, 0);                  \
        }                                                                      \
        __builtin_amdgcn_sched_barrier(0);                                     \
    }

#define QKV_STAGE(BI, KT)                                                      \
    {                                                                          \
        const size_t ko = (size_t)(KT) * 32;                                   \
        char* dA = (char*)As[BI]  + wave * 1024;                               \
        char* dQ = (char*)BQs[BI] + wave * 1024;                               \
        char* dK = (char*)BKs[BI] + wave * 1024;                               \
        char* dV = (char*)BVs[BI] + wave * 1024;                               \
        load_lds16(srcA + ko, dA);       load_lds16(srcA + ko + D64, dA + 4096);\
        load_lds16(srcQ + ko, dQ);       load_lds16(srcQ + ko + D64, dQ + 4096);\
        load_lds16(srcK + ko, dK);       load_lds16(srcK + ko + D64, dK + 4096);\
        load_lds16(srcV + ko, dV);       load_lds16(srcV + ko + D64, dV + 4096);\
    }

__global__ __launch_bounds__(256, 2) void qkv_attn(
    const u16* __restrict__ Ebf,
    const u16* __restrict__ Wqb, const u16* __restrict__ Wkb,
    const u16* __restrict__ Wvb,
    const float* __restrict__ bq, const float* __restrict__ bk,
    const float* __restrict__ bv, const float* __restrict__ qual,
    u16* __restrict__ ctx)
{
    __shared__ __align__(16) u16 As [2][128 * 32];
    __shared__ __align__(16) u16 BQs[2][128 * 32];
    __shared__ __align__(16) u16 BKs[2][128 * 32];
    __shared__ __align__(16) u16 BVs[2][128 * 32];
    __shared__ float exch[4][4][4][16];   // [wave][mi][quad][t*4+j]

    const int tid = threadIdx.x;
    const int h = blockIdx.x;            // head = n-tile
    const int m0 = blockIdx.y * 128;
    const int n0 = h * 128;

    const int wave = tid >> 6;
    const int lane = tid & 63;

    // staging geometry (see header comment)
    const int srow = wave * 16 + (lane >> 2);
    const int scol = ((lane & 3) ^ ((lane >> 3) & 3)) * 8;   // u16 units
    const u16* srcA = Ebf + (size_t)(m0 + srow) * DD + scol;
    const u16* srcQ = Wqb + (size_t)(n0 + srow) * DD + scol;
    const u16* srcK = Wkb + (size_t)(n0 + srow) * DD + scol;
    const u16* srcV = Wvb + (size_t)(n0 + srow) * DD + scol;
    const size_t D64 = (size_t)64 * DD;

    const int lrow = lane & 15;
    const int q4 = lane >> 4;
    const int wm = (wave >> 1) * 64;     // wave's 64 M-rows
    const int wn = (wave & 1) * 64;      // wave's 64 N-cols (half head)
    const int soff = (q4 ^ ((lrow >> 1) & 3)) * 16;  // swizzled slot in 64B row

    f32x4 aQ[4][4] = {};
    f32x4 aK[4][4] = {};
    f32x4 aV[4][4] = {};

    QKV_STAGE(0, 0);
    QKV_STAGE(1, 1);

    // main loop: tiles 0..61 (pairs), staging t+2 / t+3 (max 63)
#pragma unroll 1
    for (int t = 0; t < 62; t += 2) {
        PIPE_WAIT(8);          // my 8 loads for tile t done (t+1's in flight)
        QKV_COMPUTE(0);
        PIPE_FLIP();           // all waves done reading buf0
        QKV_STAGE(0, t + 2);
        PIPE_WAIT(8);
        QKV_COMPUTE(1);
        PIPE_FLIP();
        QKV_STAGE(1, t + 3);
    }
    // tail: tiles 62, 63 (no further staging; final wait must be 0)
    PIPE_WAIT(8);
    QKV_COMPUTE(0);
    PIPE_WAIT(0);
    QKV_COMPUTE(1);

    __syncthreads();   // pipeline fully drained before epilogue exch use

    // ---- epilogue: scores -> cross-wave sum -> softmax -> V combine ----
    const int quad = lane >> 4;
    const int lcol = lane & 15;

    float qb[4], kb[4], vb[4];
#pragma unroll
    for (int ni = 0; ni < 4; ++ni) {
        const int col = n0 + wn + ni * 16 + lcol;
        qb[ni] = bq[col]; kb[ni] = bk[col]; vb[ni] = bv[col];
    }

    // Phase A: per mi, partial scores over this wave's 64 cols -> exch
#pragma unroll
    for (int mi = 0; mi < 4; ++mi) {
        float ps[4][4];
#pragma unroll
        for (int t = 0; t < 4; ++t)
#pragma unroll
            for (int j = 0; j < 4; ++j) ps[t][j] = 0.f;

#pragma unroll
        for (int ni = 0; ni < 4; ++ni) {
            float qv[4], kv[4];
#pragma unroll
            for (int t = 0; t < 4; ++t) {
                qv[t] = aQ[mi][ni][t] + qb[ni];
                kv[t] = aK[mi][ni][t] + kb[ni];
            }
#pragma unroll
            for (int t = 0; t < 4; ++t)
#pragma unroll
                for (int j = 0; j < 4; ++j) ps[t][j] += qv[t] * kv[j];
        }
        // butterfly over the 16 col-lanes (bits 0..3 of lane)
#pragma unroll
        for (int t = 0; t < 4; ++t)
#pragma unroll
            for (int j = 0; j < 4; ++j) {
                ps[t][j] += __shfl_xor(ps[t][j], 1);
                ps[t][j] += __shfl_xor(ps[t][j], 2);
                ps[t][j] += __shfl_xor(ps[t][j], 4);
                ps[t][j] += __shfl_xor(ps[t][j], 8);
            }
        // one lane per quad writes the 16 values with STATIC indices
        if (lcol == 0) {
#pragma unroll
            for (int t = 0; t < 4; ++t)
#pragma unroll
                for (int j = 0; j < 4; ++j)
                    exch[wave][mi][quad][t * 4 + j] = ps[t][j];
        }
    }
    __syncthreads();

    // Phase B: full scores (own + N-partner) -> softmax -> V combine
    const float scale = 0.08838834764831845f;   // 1/sqrt(128)
#pragma unroll
    for (int mi = 0; mi < 4; ++mi) {
        const int bbat = (m0 >> 2) + (wave >> 1) * 16 + mi * 4 + quad;

        float s16[16];
#pragma unroll
        for (int v = 0; v < 16; ++v)
            s16[v] = exch[wave][mi][quad][v] + exch[wave ^ 1][mi][quad][v];

        float qj[4];
#pragma unroll
        for (int j = 0; j < 4; ++j) qj[j] = qual[bbat * 4 + j] * scale;

        float wsum[4] = {0.f, 0.f, 0.f, 0.f};
#pragma unroll
        for (int t = 0; t < 4; ++t) {
            float sm[4]; float mx = -1e30f;
#pragma unroll
            for (int j = 0; j < 4; ++j) { sm[j] = s16[t * 4 + j] * qj[j]; mx = fmaxf(mx, sm[j]); }
            float ex[4]; float se = 0.f;
#pragma unroll
            for (int j = 0; j < 4; ++j) { ex[j] = __expf(sm[j] - mx); se += ex[j]; }
            const float inv = 0.25f / se;
#pragma unroll
            for (int j = 0; j < 4; ++j) wsum[j] += ex[j] * inv;
        }

        // ctx[bbat][col] = sum_j wsum[j] * Vproj[4b+j][col] + bv[col]
        // (sum_j wsum[j] == 1, so bias coefficient is exactly 1)
#pragma unroll
        for (int ni = 0; ni < 4; ++ni) {
            const int col = n0 + wn + ni * 16 + lcol;
            float r = wsum[0] * aV[mi][ni][0] + wsum[1] * aV[mi][ni][1]
                    + wsum[2] * aV[mi][ni][2] + wsum[3] * aV[mi][ni][3] + vb[ni];
            ctx[(size_t)bbat * DD + col] = f2b(r);
        }
    }
}

// ---------------------------------------------------------------------------
// o_gemm: Y (f32) = ctx @ Wo^T + bo.  Same counted-vmcnt BK=32 dbuf
// structure (4 loads/wave per STAGE -> vmcnt(4)).
// ---------------------------------------------------------------------------
#define O_STAGE(BI, KT)                                                        \
    {                                                                          \
        const size_t ko = (size_t)(KT) * 32;                                   \
        char* dA = (char*)As[BI] + wave * 1024;                                \
        char* dB = (char*)Bs[BI] + wave * 1024;                                \
        load_lds16(srcA + ko, dA);      load_lds16(srcA + ko + D64, dA + 4096);\
        load_lds16(srcB + ko, dB);      load_lds16(srcB + ko + D64, dB + 4096);\
    }

#define O_COMPUTE(BI)                                                          \
    {                                                                          \
        bf16x8 af[4], bfr[4];                                                  \
        _Pragma("unroll")                                                      \
        for (int i = 0; i < 4; ++i)                                            \
            af[i] = *(const bf16x8*)((const char*)As[BI] +                     \
                    (wm + i * 16 + lrow) * 64 + soff);                         \
        _Pragma("unroll")                                                      \
        for (int i = 0; i < 4; ++i)                                            \
            bfr[i] = *(const bf16x8*)((const char*)Bs[BI] +                    \
                     (wn + i * 16 + lrow) * 64 + soff);                        \
        _Pragma("unroll")                                                      \
        for (int mi = 0; mi < 4; ++mi)                                         \
            _Pragma("unroll")                                                  \
            for (int ni = 0; ni < 4; ++ni)                                     \
                acc[mi][ni] = __builtin_amdgcn_mfma_f32_16x16x32_bf16(         \
                    af[mi], bfr[ni], acc[mi][ni], 0, 0, 0);                    \
    }

__global__ __launch_bounds__(256) void o_gemm(
    const u16* __restrict__ A, const u16* __restrict__ W,
    const float* __restrict__ bia, float* __restrict__ Y)
{
    __shared__ __align__(16) u16 As[2][128 * 32];
    __shared__ __align__(16) u16 Bs[2][128 * 32];

    const int tid = threadIdx.x;
    const int m0 = blockIdx.x * 128;
    const int n0 = blockIdx.y * 128;

    const int wave = tid >> 6;
    const int lane = tid & 63;

    const int srow = wave * 16 + (lane >> 2);
    const int scol = ((lane & 3) ^ ((lane >> 3) & 3)) * 8;
    const u16* srcA = A + (size_t)(m0 + srow) * DD + scol;
    const u16* srcB = W + (size_t)(n0 + srow) * DD + scol;
    const size_t D64 = (size_t)64 * DD;

    const int wm = (wave >> 1) * 64;
    const int wn = (wave & 1) * 64;
    const int lrow = lane & 15;
    const int q4 = lane >> 4;
    const int soff = (q4 ^ ((lrow >> 1) & 3)) * 16;

    f32x4 acc[4][4] = {};

    O_STAGE(0, 0);
    O_STAGE(1, 1);

#pragma unroll 1
    for (int t = 0; t < 62; t += 2) {
        PIPE_WAIT(4);
        O_COMPUTE(0);
        PIPE_FLIP();
        O_STAGE(0, t + 2);
        PIPE_WAIT(4);
        O_COMPUTE(1);
        PIPE_FLIP();
        O_STAGE(1, t + 3);
    }
    PIPE_WAIT(4);
    O_COMPUTE(0);
    PIPE_WAIT(0);
    O_COMPUTE(1);

#pragma unroll
    for (int mi = 0; mi < 4; ++mi) {
#pragma unroll
        for (int r = 0; r < 4; ++r) {
            const int grow = m0 + wm + mi * 16 + (lane >> 4) * 4 + r;
#pragma unroll
            for (int ni = 0; ni < 4; ++ni) {
                const int gcol = n0 + wn + ni * 16 + (lane & 15);
                Y[(size_t)grow * DD + gcol] = acc[mi][ni][r] + bia[gcol];
            }
        }
    }
}

// ---------------------------------------------------------------------------
// ln_kernel: residual add (precomputed resid) + LayerNorm.  One block per row.
// ---------------------------------------------------------------------------
__global__ __launch_bounds__(256) void ln_kernel(
    const float* __restrict__ Y,
    const float* __restrict__ resid,
    const float* __restrict__ gamma, const float* __restrict__ beta,
    float* __restrict__ out)
{
    const int r = blockIdx.x;
    const int tid = threadIdx.x;
    const int c = tid * 8;
    const size_t base = (size_t)r * DD + c;

    float v[8];
    {
        float4 y0 = *(const float4*)(Y + base);
        float4 y1 = *(const float4*)(Y + base + 4);
        float4 r0 = *(const float4*)(resid + base);
        float4 r1 = *(const float4*)(resid + base + 4);
        v[0] = y0.x + r0.x; v[1] = y0.y + r0.y; v[2] = y0.z + r0.z; v[3] = y0.w + r0.w;
        v[4] = y1.x + r1.x; v[5] = y1.y + r1.y; v[6] = y1.z + r1.z; v[7] = y1.w + r1.w;
    }

    float s = 0.f, sq = 0.f;
#pragma unroll
    for (int i = 0; i < 8; ++i) { s += v[i]; sq += v[i] * v[i]; }
#pragma unroll
    for (int off = 32; off >= 1; off >>= 1) {
        s += __shfl_xor(s, off);
        sq += __shfl_xor(sq, off);
    }
    __shared__ float sh[8];
    const int lane = tid & 63, wv = tid >> 6;
    if (lane == 0) { sh[wv] = s; sh[4 + wv] = sq; }
    __syncthreads();
    s = sh[0] + sh[1] + sh[2] + sh[3];
    sq = sh[4] + sh[5] + sh[6] + sh[7];

    const float invD = 1.0f / 2048.0f;
    const float mu = s * invD;
    const float rs = rsqrtf(sq * invD - mu * mu + 1e-5f);

    float4 g0 = *(const float4*)(gamma + c);
    float4 g1 = *(const float4*)(gamma + c + 4);
    float4 b0 = *(const float4*)(beta + c);
    float4 b1 = *(const float4*)(beta + c + 4);
    float gg[8] = {g0.x, g0.y, g0.z, g0.w, g1.x, g1.y, g1.z, g1.w};
    float bb[8] = {b0.x, b0.y, b0.z, b0.w, b1.x, b1.y, b1.z, b1.w};

    float o[8];
#pragma unroll
    for (int i = 0; i < 8; ++i) o[i] = (v[i] - mu) * rs * gg[i] + bb[i];
    *(float4*)(out + base)     = make_float4(o[0], o[1], o[2], o[3]);
    *(float4*)(out + base + 4) = make_float4(o[4], o[5], o[6], o[7]);
}

// ---------------------------------------------------------------------------
extern "C" void kernel_launch(void* const* d_in, const int* in_sizes, int n_in,
                              void* d_out, int out_size, void* d_ws, size_t ws_size,
                              hipStream_t stream)
{
    const float* e0   = (const float*)d_in[0];
    const float* e1   = (const float*)d_in[1];
    const float* e2   = (const float*)d_in[2];
    const float* e3   = (const float*)d_in[3];
    const float* qual = (const float*)d_in[4];
    const float* Wq   = (const float*)d_in[5];
    const float* bq   = (const float*)d_in[6];
    const float* Wk   = (const float*)d_in[7];
    const float* bk   = (const float*)d_in[8];
    const float* Wv   = (const float*)d_in[9];
    const float* bv   = (const float*)d_in[10];
    const float* Wo   = (const float*)d_in[11];
    const float* bo   = (const float*)d_in[12];
    const float* gm   = (const float*)d_in[13];
    const float* bt   = (const float*)d_in[14];

    const size_t WD = (size_t)DD * DD;            // 4,194,304
    const size_t MQ = (size_t)BB * NTT * DD;      // 33,554,432
    const size_t ED = (size_t)BB * DD;            // 8,388,608

    // workspace (u16 units): Ebf 67.1MB + W4 33.6MB + ctx 16.8MB
    // + Y 33.6MB f32 + resid 33.6MB f32 = 184.6 MB total.
    u16* Ebf = (u16*)d_ws;                        // MQ
    u16* W4  = Ebf + MQ;                          // 4*WD  (q,k,v,o)
    u16* ctx = W4 + 4 * WD;                       // ED
    float* Y = (float*)(ctx + ED);                // ED floats
    float* resid = Y + ED;                        // ED floats

    // stage 0: all conversions + residual mean in one dispatch
    cvt_all<<<dim3(12288), 256, 0, stream>>>(e0, e1, e2, e3, Wq, Wk, Wv, Wo,
                                             Ebf, W4, resid);

    // stage 1: fused QKV projection + attention -> ctx (B x D)
    qkv_attn<<<dim3(16, 128), 256, 0, stream>>>(Ebf, W4, W4 + WD, W4 + 2 * WD,
                                                bq, bk, bv, qual, ctx);

    // stage 2: O projection -> Y f32
    o_gemm<<<dim3(32, 16), 256, 0, stream>>>(ctx, W4 + 3 * WD, bo, Y);

    // stage 3: residual add + LayerNorm
    ln_kernel<<<dim3(4096), 256, 0, stream>>>(Y, resid, gm, bt,
                                              (float*)d_out);
}